// Round 1
// baseline (121.618 us; speedup 1.0000x reference)
//
#include <hip/hip_runtime.h>
#include <hip/hip_bf16.h>

#define BATCH 4096
#define NROW  8192
#define DIM   256
// temperature = 0.5 -> 1/T = 2.0

typedef __attribute__((ext_vector_type(8))) short  short8;   // 8 bf16 in 4 VGPRs
typedef __attribute__((ext_vector_type(4))) float  floatx4;  // MFMA C/D

// ---------------------------------------------------------------------------
// ws layout (bytes):
//   zf    : [0,            8 MiB)   float [8192][256] normalized fp32
//   zb    : [8 MiB,       12 MiB)   bf16  [8192][256] normalized bf16 (as ushort)
//   part  : [12 MiB, +256 KiB)      float [8][8192]   partial row sums
//   bpart : next 128 B              float [32]        per-block loss partials
// ---------------------------------------------------------------------------

__global__ void k_normalize(const float* __restrict__ z1, const float* __restrict__ z2,
                            float* __restrict__ zf, ushort* __restrict__ zb) {
  int row = blockIdx.x;            // 0..8191
  int t   = threadIdx.x;           // 0..255 == column
  const float* src = (row < BATCH) ? (z1 + (size_t)row * DIM)
                                   : (z2 + (size_t)(row - BATCH) * DIM);
  float x  = src[t];
  float ss = x * x;
#pragma unroll
  for (int off = 32; off; off >>= 1) ss += __shfl_down(ss, off, 64);
  __shared__ float sred[4];
  int wave = t >> 6, lane = t & 63;
  if (lane == 0) sred[wave] = ss;
  __syncthreads();
  float tot   = sred[0] + sred[1] + sred[2] + sred[3];
  float scale = 1.0f / fmaxf(sqrtf(tot), 1e-12f);
  float y = x * scale;
  zf[(size_t)row * DIM + t] = y;
  __hip_bfloat16 h = __float2bfloat16(y);
  zb[(size_t)row * DIM + t] = *(ushort*)&h;
}

// ---------------------------------------------------------------------------
// Kernel 2: partial row sums of exp(2*sim) over a 1024-column split.
// Block = 256 threads (4 waves). Each block: 128 rows, 1024 cols.
// Wave owns 32 rows (2 MFMA row-blocks of 16), A-frags held in registers.
// B tiles of 64 cols staged in LDS (row stride 264 bf16 to spread banks).
// MFMA 16x16x32_bf16:
//   A frag: A[m = lane&15][k = (lane>>4)*8 + j]   (8 bf16 / lane)
//   B frag: B[k = (lane>>4)*8 + j][n = lane&15]
//   C/D   : row = (lane>>4)*4 + reg, col = lane&15
// ---------------------------------------------------------------------------
__global__ __launch_bounds__(256) void k_rowsums(const ushort* __restrict__ zb,
                                                 float* __restrict__ part) {
  __shared__ __align__(16) ushort Bt[64 * 264];

  const int tid    = threadIdx.x;
  const int w      = tid >> 6;         // wave 0..3
  const int lane   = tid & 63;
  const int quad   = lane >> 4;        // 0..3
  const int l16    = lane & 15;        // 0..15
  const int rowbase = blockIdx.x * 128 + w * 32;   // this wave's rows
  const int c0base  = blockIdx.y * 1024;           // column split

  // Load A fragments once: 2 row-blocks x 8 k-steps (64 VGPRs)
  short8 Af[2][8];
#pragma unroll
  for (int rb = 0; rb < 2; rb++) {
    const ushort* p = zb + (size_t)(rowbase + rb * 16 + l16) * DIM + quad * 8;
#pragma unroll
    for (int k = 0; k < 8; k++) Af[rb][k] = *(const short8*)(p + k * 32);
  }

  float rsum[2][4] = {{0, 0, 0, 0}, {0, 0, 0, 0}};

  for (int ct = 0; ct < 16; ct++) {
    const int c0 = c0base + ct * 64;
    __syncthreads();   // previous tile's reads done before overwrite
    {
      // stage 64 cols x 256 k (32 KB) into LDS, 8 x uint4 per thread
      const uint4* src = (const uint4*)(zb + (size_t)c0 * DIM);
#pragma unroll
      for (int i = 0; i < 8; i++) {
        int idx = tid + i * 256;
        int r = idx >> 5;        // row within tile
        int c = idx & 31;        // 16B chunk within row
        *(uint4*)(&Bt[r * 264 + c * 8]) = src[r * 32 + c];
      }
    }
    __syncthreads();

#pragma unroll
    for (int cs = 0; cs < 4; cs++) {
      const ushort* bp = &Bt[(cs * 16 + l16) * 264 + quad * 8];
      floatx4 acc0 = {0.f, 0.f, 0.f, 0.f};
      floatx4 acc1 = {0.f, 0.f, 0.f, 0.f};
#pragma unroll
      for (int k = 0; k < 8; k++) {
        short8 Bf = *(const short8*)(bp + k * 32);
        acc0 = __builtin_amdgcn_mfma_f32_16x16x32_bf16(Af[0][k], Bf, acc0, 0, 0, 0);
        acc1 = __builtin_amdgcn_mfma_f32_16x16x32_bf16(Af[1][k], Bf, acc1, 0, 0, 0);
      }
#pragma unroll
      for (int r = 0; r < 4; r++) {
        rsum[0][r] += __expf(2.0f * acc0[r]);
        rsum[1][r] += __expf(2.0f * acc1[r]);
      }
    }
  }

  // reduce across the 16 lanes (columns) within each quad group
#pragma unroll
  for (int rb = 0; rb < 2; rb++)
#pragma unroll
    for (int r = 0; r < 4; r++) {
      float v = rsum[rb][r];
#pragma unroll
      for (int off = 1; off < 16; off <<= 1) v += __shfl_xor(v, off, 64);
      rsum[rb][r] = v;
    }

  if (l16 == 0) {
#pragma unroll
    for (int rb = 0; rb < 2; rb++)
#pragma unroll
      for (int r = 0; r < 4; r++) {
        int row = rowbase + rb * 16 + quad * 4 + r;
        part[(size_t)blockIdx.y * NROW + row] = rsum[rb][r];
      }
  }
}

// ---------------------------------------------------------------------------
// Kernel 3: per-row loss term, block partial sums. 32 blocks x 256 threads.
//   t_j = log(neg_j) - 2*dot(z_j, z_pair)
//   neg_j = sum_splits part[s][j] - exp(2*selfdot_j)
// ---------------------------------------------------------------------------
__global__ void k_rowterm(const float* __restrict__ zf, const float* __restrict__ part,
                          float* __restrict__ bpart) {
  int j  = blockIdx.x * 256 + threadIdx.x;
  int pj = (j + BATCH) & (NROW - 1);
  const float4* a = (const float4*)(zf + (size_t)j * DIM);
  const float4* b = (const float4*)(zf + (size_t)pj * DIM);
  float dp = 0.f, sd = 0.f;
#pragma unroll 8
  for (int i = 0; i < DIM / 4; i++) {
    float4 x = a[i], y = b[i];
    dp += x.x * y.x + x.y * y.y + x.z * y.z + x.w * y.w;
    sd += x.x * x.x + x.y * x.y + x.z * x.z + x.w * x.w;
  }
  float neg = 0.f;
#pragma unroll
  for (int s = 0; s < 8; s++) neg += part[(size_t)s * NROW + j];
  neg -= expf(2.0f * sd);
  float t = logf(neg) - 2.0f * dp;

  // block reduce 256 -> 1
#pragma unroll
  for (int off = 32; off; off >>= 1) t += __shfl_down(t, off, 64);
  __shared__ float sred[4];
  int wave = threadIdx.x >> 6, lane = threadIdx.x & 63;
  if (lane == 0) sred[wave] = t;
  __syncthreads();
  if (threadIdx.x == 0) bpart[blockIdx.x] = sred[0] + sred[1] + sred[2] + sred[3];
}

__global__ void k_final(const float* __restrict__ bpart, float* __restrict__ out) {
  int t = threadIdx.x;   // 64 threads
  float v = (t < 32) ? bpart[t] : 0.f;
#pragma unroll
  for (int off = 32; off; off >>= 1) v += __shfl_down(v, off, 64);
  if (t == 0) out[0] = v / (float)NROW;
}

extern "C" void kernel_launch(void* const* d_in, const int* in_sizes, int n_in,
                              void* d_out, int out_size, void* d_ws, size_t ws_size,
                              hipStream_t stream) {
  const float* z1 = (const float*)d_in[0];
  const float* z2 = (const float*)d_in[1];
  float* out = (float*)d_out;

  char* ws = (char*)d_ws;
  float*  zf    = (float*)ws;                                         // 8 MiB
  ushort* zb    = (ushort*)(ws + (size_t)8 * 1024 * 1024);            // 4 MiB
  float*  part  = (float*)(ws + (size_t)12 * 1024 * 1024);            // 256 KiB
  float*  bpart = (float*)(ws + (size_t)12 * 1024 * 1024 + 8 * NROW * 4);

  k_normalize<<<NROW, 256, 0, stream>>>(z1, z2, zf, zb);
  k_rowsums<<<dim3(64, 8), 256, 0, stream>>>(zb, part);
  k_rowterm<<<32, 256, 0, stream>>>(zf, part, bpart);
  k_final<<<1, 64, 0, stream>>>(bpart, out);
}

// Round 2
// 104.815 us; speedup vs baseline: 1.1603x; 1.1603x over previous
//
#include <hip/hip_runtime.h>
#include <hip/hip_bf16.h>

#define BATCH 4096
#define NROW  8192
#define DIM   256
// temperature = 0.5 -> 1/T = 2.0

typedef __attribute__((ext_vector_type(8))) short  short8;   // 8 bf16 in 4 VGPRs
typedef __attribute__((ext_vector_type(4))) float  floatx4;  // MFMA C/D

// ---------------------------------------------------------------------------
// ws layout (bytes):
//   zf    : [0,        8 MiB)    float [8192][256] normalized fp32
//   zb    : [8, 12 MiB)          bf16  [8192][256] normalized (as ushort)
//   part  : [12 MiB, +512 KiB)   float [16][8192]  partial row sums
//   bpart : next 8 KiB           float [2048]      per-block loss partials
// ---------------------------------------------------------------------------

// Wave-per-row normalize: 4 rows/block, float4 loads, shfl-only reduction.
__global__ __launch_bounds__(256) void k_normalize(const float* __restrict__ z1,
                                                   const float* __restrict__ z2,
                                                   float* __restrict__ zf,
                                                   ushort* __restrict__ zb) {
  int row  = blockIdx.x * 4 + (threadIdx.x >> 6);   // 0..8191
  int lane = threadIdx.x & 63;
  const float4* src = (row < BATCH) ? (const float4*)(z1 + (size_t)row * DIM)
                                    : (const float4*)(z2 + (size_t)(row - BATCH) * DIM);
  float4 v = src[lane];
  float ss = v.x * v.x + v.y * v.y + v.z * v.z + v.w * v.w;
#pragma unroll
  for (int off = 1; off < 64; off <<= 1) ss += __shfl_xor(ss, off, 64);
  float scale = 1.0f / fmaxf(sqrtf(ss), 1e-12f);
  float4 y = {v.x * scale, v.y * scale, v.z * scale, v.w * scale};
  ((float4*)(zf + (size_t)row * DIM))[lane] = y;
  __hip_bfloat16 h0 = __float2bfloat16(y.x), h1 = __float2bfloat16(y.y);
  __hip_bfloat16 h2 = __float2bfloat16(y.z), h3 = __float2bfloat16(y.w);
  ushort4 hb = {*(ushort*)&h0, *(ushort*)&h1, *(ushort*)&h2, *(ushort*)&h3};
  ((ushort4*)(zb + (size_t)row * DIM))[lane] = hb;
}

// ---------------------------------------------------------------------------
// Kernel 2: partial row sums of exp(2*sim) over a 512-column split.
// Block = 256 threads (4 waves). Block: 256 rows, 512 cols.
// Wave owns 64 rows (4 MFMA row-blocks of 16), A-frags pinned in 128 VGPRs.
// B tiles of 64 cols staged in LDS (row stride 264 bf16). Each B-frag read
// feeds 4 MFMAs (the LDS-pipe relief vs R1's 2).
// MFMA 16x16x32_bf16:
//   A frag: A[m = lane&15][k = (lane>>4)*8 + j]
//   B frag: B[k = (lane>>4)*8 + j][n = lane&15]
//   C/D   : row = (lane>>4)*4 + reg, col = lane&15
// ---------------------------------------------------------------------------
__global__ __launch_bounds__(256, 2) void k_rowsums(const ushort* __restrict__ zb,
                                                    float* __restrict__ part) {
  __shared__ __align__(16) ushort Bt[64 * 264];

  const int tid     = threadIdx.x;
  const int w       = tid >> 6;
  const int lane    = tid & 63;
  const int quad    = lane >> 4;
  const int l16     = lane & 15;
  const int rowbase = blockIdx.x * 256 + w * 64;
  const int c0base  = blockIdx.y * 512;

  // Pin A fragments: 4 row-blocks x 8 k-steps = 128 VGPRs
  short8 Af[4][8];
#pragma unroll
  for (int rb = 0; rb < 4; rb++) {
    const ushort* p = zb + (size_t)(rowbase + rb * 16 + l16) * DIM + quad * 8;
#pragma unroll
    for (int k = 0; k < 8; k++) Af[rb][k] = *(const short8*)(p + k * 32);
  }

  float rsum[4][4];
#pragma unroll
  for (int rb = 0; rb < 4; rb++)
#pragma unroll
    for (int r = 0; r < 4; r++) rsum[rb][r] = 0.f;

  for (int ct = 0; ct < 8; ct++) {
    const int c0 = c0base + ct * 64;
    __syncthreads();
    {
      const uint4* src = (const uint4*)(zb + (size_t)c0 * DIM);
#pragma unroll
      for (int i = 0; i < 8; i++) {
        int idx = tid + i * 256;
        int r = idx >> 5, c = idx & 31;
        *(uint4*)(&Bt[r * 264 + c * 8]) = src[r * 32 + c];
      }
    }
    __syncthreads();

#pragma unroll
    for (int cs = 0; cs < 4; cs++) {
      const ushort* bp = &Bt[(cs * 16 + l16) * 264 + quad * 8];
      floatx4 acc[4];
#pragma unroll
      for (int rb = 0; rb < 4; rb++) acc[rb] = (floatx4){0.f, 0.f, 0.f, 0.f};
#pragma unroll
      for (int k = 0; k < 8; k++) {
        short8 Bf = *(const short8*)(bp + k * 32);
#pragma unroll
        for (int rb = 0; rb < 4; rb++)
          acc[rb] = __builtin_amdgcn_mfma_f32_16x16x32_bf16(Af[rb][k], Bf, acc[rb], 0, 0, 0);
      }
#pragma unroll
      for (int rb = 0; rb < 4; rb++)
#pragma unroll
        for (int r = 0; r < 4; r++) rsum[rb][r] += __expf(2.0f * acc[rb][r]);
    }
  }

  // reduce across the 16 column-lanes within each quad group
#pragma unroll
  for (int rb = 0; rb < 4; rb++)
#pragma unroll
    for (int r = 0; r < 4; r++) {
      float v = rsum[rb][r];
#pragma unroll
      for (int off = 1; off < 16; off <<= 1) v += __shfl_xor(v, off, 64);
      rsum[rb][r] = v;
    }

  if (l16 == 0) {
#pragma unroll
    for (int rb = 0; rb < 4; rb++)
#pragma unroll
      for (int r = 0; r < 4; r++) {
        int row = rowbase + rb * 16 + quad * 4 + r;
        part[(size_t)blockIdx.y * NROW + row] = rsum[rb][r];
      }
  }
}

// ---------------------------------------------------------------------------
// Kernel 3: wave-per-row loss term. 2048 blocks x 256 threads (4 rows/block).
//   t_j = log(neg_j) - 2*dot(z_j, z_pair)
//   neg_j = sum_s part[s][j] - exp(2*selfdot_j)
// ---------------------------------------------------------------------------
__global__ __launch_bounds__(256) void k_rowterm(const float* __restrict__ zf,
                                                 const float* __restrict__ part,
                                                 float* __restrict__ bpart) {
  int j    = blockIdx.x * 4 + (threadIdx.x >> 6);
  int lane = threadIdx.x & 63;
  int pj   = (j + BATCH) & (NROW - 1);
  const float4* a = (const float4*)(zf + (size_t)j * DIM);
  const float4* b = (const float4*)(zf + (size_t)pj * DIM);
  float4 x = a[lane], y = b[lane];
  float dp = x.x * y.x + x.y * y.y + x.z * y.z + x.w * y.w;
  float sd = x.x * x.x + x.y * x.y + x.z * x.z + x.w * x.w;
  float ng = (lane < 16) ? part[(size_t)lane * NROW + j] : 0.f;
#pragma unroll
  for (int off = 1; off < 64; off <<= 1) {
    dp += __shfl_xor(dp, off, 64);
    sd += __shfl_xor(sd, off, 64);
    ng += __shfl_xor(ng, off, 64);
  }
  __shared__ float sred[4];
  if (lane == 0) {
    float neg = ng - expf(2.0f * sd);
    sred[threadIdx.x >> 6] = logf(neg) - 2.0f * dp;
  }
  __syncthreads();
  if (threadIdx.x == 0)
    bpart[blockIdx.x] = sred[0] + sred[1] + sred[2] + sred[3];
}

__global__ void k_final(const float* __restrict__ bpart, float* __restrict__ out) {
  int t = threadIdx.x;  // 256 threads
  float v = 0.f;
#pragma unroll
  for (int i = 0; i < 8; i++) v += bpart[t + i * 256];
  int lane = t & 63;
#pragma unroll
  for (int off = 1; off < 64; off <<= 1) v += __shfl_xor(v, off, 64);
  __shared__ float sred[4];
  if (lane == 0) sred[t >> 6] = v;
  __syncthreads();
  if (t == 0) out[0] = (sred[0] + sred[1] + sred[2] + sred[3]) / (float)NROW;
}

extern "C" void kernel_launch(void* const* d_in, const int* in_sizes, int n_in,
                              void* d_out, int out_size, void* d_ws, size_t ws_size,
                              hipStream_t stream) {
  const float* z1 = (const float*)d_in[0];
  const float* z2 = (const float*)d_in[1];
  float* out = (float*)d_out;

  char* ws = (char*)d_ws;
  float*  zf    = (float*)ws;                                          // 8 MiB
  ushort* zb    = (ushort*)(ws + (size_t)8 * 1024 * 1024);             // 4 MiB
  float*  part  = (float*)(ws + (size_t)12 * 1024 * 1024);             // 512 KiB
  float*  bpart = (float*)(ws + (size_t)12 * 1024 * 1024 + 16 * NROW * 4);

  k_normalize<<<NROW / 4, 256, 0, stream>>>(z1, z2, zf, zb);
  k_rowsums<<<dim3(32, 16), 256, 0, stream>>>(zb, part);
  k_rowterm<<<NROW / 4, 256, 0, stream>>>(zf, part, bpart);
  k_final<<<1, 256, 0, stream>>>(bpart, out);
}